// Round 8
// baseline (351.357 us; speedup 1.0000x reference)
//
#include <hip/hip_runtime.h>
#include <hip/hip_bf16.h>
#include <type_traits>

typedef __bf16 bf16;
typedef __bf16 bf16x2 __attribute__((ext_vector_type(2)));
typedef __bf16 bf16x4 __attribute__((ext_vector_type(4)));
typedef __bf16 bf16x8 __attribute__((ext_vector_type(8)));
typedef float f32x4 __attribute__((ext_vector_type(4)));

#define AS1 __attribute__((address_space(1)))
#define AS3 __attribute__((address_space(3)))

// 0.125 (1/sqrt(64)) * log2(e): folded into Q so attn scores are log2-domain.
#define KAPPA 0.180336880111f

__device__ __forceinline__ void load_lds16(const void* g, void* l) {
  __builtin_amdgcn_global_load_lds((AS1 void*)g, (AS3 void*)l, 16, 0, 0);
}
__device__ __forceinline__ float exp2_fast(float x) {
  return __builtin_amdgcn_exp2f(x);
}

// ---------------------------------------------------------------------------
// All fp32->bf16 conversions in one launch.
// ---------------------------------------------------------------------------
__global__ void f2b_all(const float* __restrict__ x, const float* __restrict__ wq,
                        const float* __restrict__ wk, const float* __restrict__ wv,
                        const float* __restrict__ wo, bf16* __restrict__ xb,
                        bf16* __restrict__ wqkv, bf16* __restrict__ wob) {
  int bid = blockIdx.x;
  const float* src;
  bf16* dst;
  int off;
  if (bid < 8192) { src = x; dst = xb; off = bid; }
  else if (bid < 12288) { src = wq; dst = wqkv; off = bid - 8192; }
  else if (bid < 13312) { src = wk; dst = wqkv + 4194304; off = bid - 12288; }
  else if (bid < 14336) { src = wv; dst = wqkv + 5242880; off = bid - 13312; }
  else { src = wo; dst = wob; off = bid - 14336; }
  int i = (off * 256 + threadIdx.x) * 4;
  float4 v = *(const float4*)(src + i);
  bf16x4 o = {(bf16)v.x, (bf16)v.y, (bf16)v.z, (bf16)v.w};
  *(bf16x4*)(dst + i) = o;
}

// ---------------------------------------------------------------------------
// Fused QKV projection GEMM: [4096 x 2048] @ [3072 x 2048]^T, 128x128 tile,
// BK=64, 128B LDS rows xor-swizzled (seg ^= row&7) -- 0 bank conflicts (R7).
// Epilogue: bn<16 Q+rope*KAPPA -> Qro (B,32,S,64); bn<20 K+rope -> Kro
// (B,8,S,64); else V^T -> Vt (B,8,64,S).
// ---------------------------------------------------------------------------
__global__ __launch_bounds__(256) void gemm_qkv(const bf16* __restrict__ A,
                                                const bf16* __restrict__ Bw,
                                                const float* __restrict__ fc,
                                                const float* __restrict__ fs,
                                                bf16* __restrict__ Qro,
                                                bf16* __restrict__ Kro,
                                                bf16* __restrict__ Vt) {
  const int K = 2048;
  __shared__ bf16 As[128][64];
  __shared__ bf16 Bs[128][64];
  const int t = threadIdx.x;
  const int wave = t >> 6, lane = t & 63, qd = lane >> 4, ln = lane & 15;
  const int wm = (wave >> 1) * 64;
  const int wn = (wave & 1) * 64;
  const int bn = blockIdx.x;
  const size_t bm = (size_t)blockIdx.y * 128;

  const bf16* Ab = A + bm * (size_t)K;
  const bf16* Bb = Bw + (size_t)bn * 128 * K;

  f32x4 acc[4][4] = {};

  for (int k0 = 0; k0 < K; k0 += 64) {
#pragma unroll
    for (int i = 0; i < 4; i++) {
      int e = i * 256 + t;
      int ro = e >> 3, gs = (e & 7) ^ (ro & 7);
      load_lds16(Ab + (size_t)ro * K + k0 + gs * 8,
                 (char*)As + i * 4096 + wave * 1024);
      load_lds16(Bb + (size_t)ro * K + k0 + gs * 8,
                 (char*)Bs + i * 4096 + wave * 1024);
    }
    __syncthreads();

#pragma unroll
    for (int kk = 0; kk < 2; kk++) {
      bf16x8 af[4], bfr[4];
#pragma unroll
      for (int i = 0; i < 4; i++) {
        int row = wm + i * 16 + ln;
        int ps = (kk * 4 + qd) ^ (row & 7);
        af[i] = *(const bf16x8*)((const char*)As + row * 128 + ps * 16);
      }
#pragma unroll
      for (int j = 0; j < 4; j++) {
        int row = wn + j * 16 + ln;
        int ps = (kk * 4 + qd) ^ (row & 7);
        bfr[j] = *(const bf16x8*)((const char*)Bs + row * 128 + ps * 16);
      }
#pragma unroll
      for (int i = 0; i < 4; i++)
#pragma unroll
        for (int j = 0; j < 4; j++)
          acc[i][j] = __builtin_amdgcn_mfma_f32_16x16x32_bf16(af[i], bfr[j],
                                                              acc[i][j], 0, 0, 0);
    }
    __syncthreads();
  }

  // ---- epilogue ----
  const int b = (int)(bm >> 11);
  const int sb = (int)(bm & 2047) + wm;
  const bool odd = ln & 1;

  if (bn < 20) {  // Q or K: rope, head-major output
    const bool isQ = bn < 16;
    const float kap = isQ ? KAPPA : 1.0f;
    const int hh = isQ ? (bn * 2 + (wn >> 6)) : ((bn - 16) * 2 + (wn >> 6));
    bf16* dst = isQ ? (Qro + ((size_t)(b * 32 + hh) * 2048) * 64)
                    : (Kro + ((size_t)(b * 8 + hh) * 2048) * 64);
#pragma unroll
    for (int i = 0; i < 4; i++) {
#pragma unroll
      for (int j = 0; j < 4; j++) {
        const int d = j * 16 + ln;
        const int i_f = d >> 1;
#pragma unroll
        for (int r = 0; r < 4; r++) {
          int s = sb + i * 16 + qd * 4 + r;
          float v = acc[i][j][r];
          float p = __shfl_xor(v, 1);
          float cv = fc[s * 32 + i_f] * kap;
          float sv = fs[s * 32 + i_f] * kap;
          float o = odd ? (p * sv + v * cv) : (v * cv - p * sv);
          dst[(size_t)s * 64 + d] = (bf16)o;
        }
      }
    }
  } else {  // V: write transposed (B,8,64,S)
    const int kh = (bn - 20) * 2 + (wn >> 6);
#pragma unroll
    for (int i = 0; i < 4; i++)
#pragma unroll
      for (int j = 0; j < 4; j++) {
        const int d = j * 16 + ln;
        int s = sb + i * 16 + qd * 4;
        bf16x4 ov = {(bf16)acc[i][j][0], (bf16)acc[i][j][1],
                     (bf16)acc[i][j][2], (bf16)acc[i][j][3]};
        *(bf16x4*)&Vt[((size_t)(b * 8 + kh) * 64 + d) * 2048 + s] = ov;
      }
  }
}

// ---------------------------------------------------------------------------
// Output projection GEMM: 128x128 tile, BK=64, split-K=2 (grid 16x32x2 =
// 1024 blocks = 4/CU). Partial sums combined via native fp32 atomic add
// into zero-initialized d_out.
// ---------------------------------------------------------------------------
__global__ __launch_bounds__(256) void gemm_out_sk(const bf16* __restrict__ A,
                                                   const bf16* __restrict__ Bw,
                                                   float* __restrict__ C) {
  const int K = 2048;
  __shared__ bf16 As[128][64];
  __shared__ bf16 Bs[128][64];
  const int t = threadIdx.x;
  const int wave = t >> 6, lane = t & 63, qd = lane >> 4, ln = lane & 15;
  const int wm = (wave >> 1) * 64;
  const int wn = (wave & 1) * 64;
  const size_t bm = (size_t)blockIdx.y * 128;
  const size_t bn = (size_t)blockIdx.x * 128;
  const int z = blockIdx.z;

  const bf16* Ab = A + bm * (size_t)K + z * 1024;
  const bf16* Bb = Bw + bn * (size_t)K + z * 1024;

  f32x4 acc[4][4] = {};

  for (int k0 = 0; k0 < 1024; k0 += 64) {
#pragma unroll
    for (int i = 0; i < 4; i++) {
      int e = i * 256 + t;
      int ro = e >> 3, gs = (e & 7) ^ (ro & 7);
      load_lds16(Ab + (size_t)ro * K + k0 + gs * 8,
                 (char*)As + i * 4096 + wave * 1024);
      load_lds16(Bb + (size_t)ro * K + k0 + gs * 8,
                 (char*)Bs + i * 4096 + wave * 1024);
    }
    __syncthreads();

#pragma unroll
    for (int kk = 0; kk < 2; kk++) {
      bf16x8 af[4], bfr[4];
#pragma unroll
      for (int i = 0; i < 4; i++) {
        int row = wm + i * 16 + ln;
        int ps = (kk * 4 + qd) ^ (row & 7);
        af[i] = *(const bf16x8*)((const char*)As + row * 128 + ps * 16);
      }
#pragma unroll
      for (int j = 0; j < 4; j++) {
        int row = wn + j * 16 + ln;
        int ps = (kk * 4 + qd) ^ (row & 7);
        bfr[j] = *(const bf16x8*)((const char*)Bs + row * 128 + ps * 16);
      }
#pragma unroll
      for (int i = 0; i < 4; i++)
#pragma unroll
        for (int j = 0; j < 4; j++)
          acc[i][j] = __builtin_amdgcn_mfma_f32_16x16x32_bf16(af[i], bfr[j],
                                                              acc[i][j], 0, 0, 0);
    }
    __syncthreads();
  }

#pragma unroll
  for (int i = 0; i < 4; i++)
#pragma unroll
    for (int j = 0; j < 4; j++)
#pragma unroll
      for (int r = 0; r < 4; r++) {
        size_t row = bm + wm + i * 16 + qd * 4 + r;
        size_t col = bn + wn + j * 16 + ln;
        unsafeAtomicAdd(&C[row * 2048 + col], acc[i][j][r]);
      }
}

// ---------------------------------------------------------------------------
// Flash attention, S^T form, causal, fixed-point log2 softmax p = 2^(s-16).
// Q-tile 256 (wave owns 64 q rows), K-block 64. Q fragments cached in
// registers (loop-invariant). LDS 80 KB -> 2 blocks/CU.
// Q:(B,32,S,64)  K:(B,8,S,64)  Vt:(B,8,64,S)  ->  O:(B,S,32,64)
// ---------------------------------------------------------------------------
__global__ __launch_bounds__(256, 2) void attn_fwd(const bf16* __restrict__ Q,
                                                   const bf16* __restrict__ Kg,
                                                   const bf16* __restrict__ Vg,
                                                   bf16* __restrict__ O) {
  __shared__ bf16 Qs[256][64];  // 32 KB
  __shared__ bf16 Ks[64][64];   // 8 KB
  __shared__ bf16 Vs[64][64];   // 8 KB  [d][k]
  __shared__ bf16 Ps[256][64];  // 32 KB [q][k], swizzled
  const int t = threadIdx.x;
  const int wave = t >> 6, lane = t & 63, qd = lane >> 4, ln = lane & 15;
  const int bid = blockIdx.x;
  const int qt = 7 - (bid >> 6);  // longest blocks dispatch first
  const int bh = bid & 63;
  const int b = bh >> 5, h = bh & 31, kh = h >> 2;
  const bf16* Qb = Q + ((size_t)(b * 32 + h) * 2048 + qt * 256) * 64;
  const bf16* Kb = Kg + (size_t)(b * 8 + kh) * 2048 * 64;
  const bf16* Vb = Vg + (size_t)(b * 8 + kh) * 64 * 2048;
  char* PsB = (char*)Ps;

  // stage Q tile 256x64 (32 KB = 8 rounds)
#pragma unroll
  for (int i = 0; i < 8; i++) {
    int e = i * 256 + t;
    int row = e >> 3, sg = (e & 7) ^ (row & 7);
    load_lds16(Qb + (size_t)row * 64 + sg * 8, (char*)Qs + i * 4096 + wave * 1024);
  }

  f32x4 o_acc[4][4] = {};          // [dj][mi]
  float l_st[4] = {0.f, 0.f, 0.f, 0.f};
  bf16x8 bq[4][2];                 // register-cached Q fragments
  const int q0 = qt * 256 + wave * 64;
  const int nkb = 4 * qt + 4;

  for (int kb = 0; kb < nkb; kb++) {
    __syncthreads();
#pragma unroll
    for (int i = 0; i < 2; i++) {
      int e = i * 256 + t;
      int row = e >> 3, sg = (e & 7) ^ (row & 7);
      load_lds16(Kb + (size_t)(kb * 64 + row) * 64 + sg * 8,
                 (char*)Ks + i * 4096 + wave * 1024);
      load_lds16(Vb + (size_t)row * 2048 + kb * 64 + sg * 8,
                 (char*)Vs + i * 4096 + wave * 1024);
    }
    __syncthreads();

    if (kb == 0) {  // Q now staged: cache fragments in registers
#pragma unroll
      for (int mi = 0; mi < 4; mi++)
#pragma unroll
        for (int kk = 0; kk < 2; kk++) {
          int row = wave * 64 + mi * 16 + ln;
          int ph = (kk * 4 + qd) ^ (ln & 7);
          bq[mi][kk] = *(const bf16x8*)((const char*)Qs + row * 128 + ph * 16);
        }
    }

    // S^T = K*Q^T : s_acc[j][mi], row k = j*16+qd*4+r, col q = mi*16+ln
    f32x4 s_acc[4][4] = {};
#pragma unroll
    for (int kk = 0; kk < 2; kk++) {
      bf16x8 ak[4];
#pragma unroll
      for (int j = 0; j < 4; j++) {
        int row = j * 16 + ln;
        int ph = (kk * 4 + qd) ^ (ln & 7);
        ak[j] = *(const bf16x8*)((const char*)Ks + row * 128 + ph * 16);
      }
#pragma unroll
      for (int j = 0; j < 4; j++)
#pragma unroll
        for (int mi = 0; mi < 4; mi++)
          s_acc[j][mi] = __builtin_amdgcn_mfma_f32_16x16x32_bf16(
              ak[j], bq[mi][kk], s_acc[j][mi], 0, 0, 0);
    }

    // fixed-point softmax: p = 2^(s-16); masked -> exact 0
    auto smax = [&](auto maskc) {
      constexpr bool MASK = decltype(maskc)::value;
#pragma unroll
      for (int mi = 0; mi < 4; mi++) {
        const int qv = q0 + mi * 16 + ln;
        const int prow = wave * 64 + mi * 16 + ln;
        float rs = 0.f;
#pragma unroll
        for (int j = 0; j < 4; j++) {
          bf16x4 pk;
#pragma unroll
          for (int r = 0; r < 4; r++) {
            float s = s_acc[j][mi][r];
            if (MASK) {
              int k_glob = kb * 64 + j * 16 + qd * 4 + r;
              if (k_glob > qv) s = -1e5f;
            }
            float pv = exp2_fast(s - 16.f);
            rs += pv;
            pk[r] = (bf16)pv;
          }
          int ps = (j * 2 + (qd >> 1)) ^ (ln & 7);
          *(bf16x4*)(PsB + prow * 128 + ps * 16 + (qd & 1) * 8) = pk;
        }
        l_st[mi] += rs;
      }
    };
    if (kb * 64 + 63 > q0) smax(std::true_type{});
    else smax(std::false_type{});

    // O^T += V^T * P^T  (Ps wave-private; lgkmcnt orders write->read)
#pragma unroll
    for (int kk = 0; kk < 2; kk++) {
      bf16x8 av[4], bp[4];
#pragma unroll
      for (int dj = 0; dj < 4; dj++) {
        int row = dj * 16 + ln;
        int ph = (kk * 4 + qd) ^ (ln & 7);
        av[dj] = *(const bf16x8*)((const char*)Vs + row * 128 + ph * 16);
      }
#pragma unroll
      for (int mi = 0; mi < 4; mi++) {
        int prow = wave * 64 + mi * 16 + ln;
        int ph = (kk * 4 + qd) ^ (ln & 7);
        bp[mi] = *(const bf16x8*)(PsB + prow * 128 + ph * 16);
      }
#pragma unroll
      for (int dj = 0; dj < 4; dj++)
#pragma unroll
        for (int mi = 0; mi < 4; mi++)
          o_acc[dj][mi] = __builtin_amdgcn_mfma_f32_16x16x32_bf16(
              av[dj], bp[mi], o_acc[dj][mi], 0, 0, 0);
    }
  }

  // epilogue: reduce l across quads (each quad summed a disjoint k-subset)
#pragma unroll
  for (int mi = 0; mi < 4; mi++) {
    float lt = l_st[mi];
    lt += __shfl_xor(lt, 16);
    lt += __shfl_xor(lt, 32);
    float inv = 1.f / lt;
    int q_idx = qt * 256 + wave * 64 + mi * 16 + ln;
#pragma unroll
    for (int dj = 0; dj < 4; dj++) {
      bf16x4 ov;
#pragma unroll
      for (int r = 0; r < 4; r++) ov[r] = (bf16)(o_acc[dj][mi][r] * inv);
      *(bf16x4*)&O[((size_t)(b * 2048 + q_idx) * 32 + h) * 64 + dj * 16 + qd * 4] = ov;
    }
  }
}

// ---------------------------------------------------------------------------
extern "C" void kernel_launch(void* const* d_in, const int* in_sizes, int n_in,
                              void* d_out, int out_size, void* d_ws,
                              size_t ws_size, hipStream_t stream) {
  const float* x = (const float*)d_in[0];
  const float* fc = (const float*)d_in[1];
  const float* fs = (const float*)d_in[2];
  const float* wq = (const float*)d_in[3];
  const float* wk = (const float*)d_in[4];
  const float* wv = (const float*)d_in[5];
  const float* wo = (const float*)d_in[6];
  float* out = (float*)d_out;

  char* ws = (char*)d_ws;
  const size_t MB = (size_t)1 << 20;
  bf16* xb   = (bf16*)(ws + 0 * MB);   // 16 MB (4096,2048)
  bf16* wqkv = (bf16*)(ws + 16 * MB);  // 12 MB (3072,2048)
  bf16* wob  = (bf16*)(ws + 28 * MB);  // 8 MB
  bf16* Qro  = (bf16*)(ws + 36 * MB);  // 16 MB (B,32,S,64), roped*KAPPA
  bf16* Kro  = (bf16*)(ws + 52 * MB);  // 4 MB  (B,8,S,64), roped
  bf16* Vt   = (bf16*)(ws + 56 * MB);  // 4 MB  (B,8,64,S)
  bf16* Oa   = (bf16*)(ws + 60 * MB);  // 16 MB (B,S,32,64)

  dim3 blk(256);
  hipMemsetAsync(out, 0, (size_t)4096 * 2048 * 4, stream);
  f2b_all<<<18432, blk, 0, stream>>>(x, wq, wk, wv, wo, xb, wqkv, wob);
  gemm_qkv<<<dim3(24, 32), blk, 0, stream>>>(xb, wqkv, fc, fs, Qro, Kro, Vt);
  attn_fwd<<<512, blk, 0, stream>>>(Qro, Kro, Vt, Oa);
  gemm_out_sk<<<dim3(16, 32, 2), blk, 0, stream>>>(Oa, wob, out);
}